// Round 10
// baseline (18.980 us; speedup 1.0000x reference)
//
#include <hip/hip_runtime.h>

// RBF network, single fused kernel (one graph node).
// R8 base with ONE change: f-split wave mapping in the main loop.
//   wave = (fh, wh): fh = f-half of each chunk, wh = 128-h slice; lane owns 2 h,
//   ALL 8 rows (acc[8][2]). Each c element is read from LDS by exactly one wave
//   (read-once floor, halves main-loop c LDS traffic). f-half partials merged
//   through LDS after the main loop.
// inputs:  x[B=2048][F=128], centers c[H=512][F=128], sigma[1], W[O=10][H=512], b[O=10]

constexpr int Fdim = 128;
constexpr int Hdim = 512;
constexpr int Odim = 10;
constexpr int BM   = 8;          // rows per block
constexpr int KC   = 32;         // F chunk resident in LDS
constexpr int NCH  = Fdim / KC;  // 4
constexpr int LDC  = 513;        // cT row stride
constexpr int LDXT = 12;         // xT row stride
constexpr int LDR  = 516;        // rbf_s row stride

__global__ __launch_bounds__(512, 1) void rbf_all(
    const float* __restrict__ x,
    const float* __restrict__ c,
    const float* __restrict__ sigmap,
    const float* __restrict__ W,
    const float* __restrict__ bias,
    float* __restrict__ out)
{
    __shared__ float cT[KC][LDC];        // 65.7 KB
    __shared__ float xT[Fdim][LDXT];     //  6.1 KB
    __shared__ float rbf_s[BM][LDR];     // 16.5 KB (also the f-half merge buffer)
    __shared__ float po_s[BM][8][Odim];  //  2.5 KB
    __shared__ float xn_s[BM];
    __shared__ float cn_s[Hdim];         // total ~93 KB

    const int tid  = threadIdx.x;
    const int lane = tid & 63;
    const int wave = tid >> 6;          // 0..7
    const int fh   = wave >> 2;         // f-half of each chunk
    const int wh   = wave & 3;          // h in [wh*128, wh*128+128)
    const int row0 = blockIdx.x * BM;

    const float4* x4 = reinterpret_cast<const float4*>(x);
    const float4* c4 = reinterpret_cast<const float4*>(c);

    // ---- stage ALL x, transposed (once), + row norms
    if (tid < 256) {
        int r  = tid >> 5;    // 0..7
        int fq = tid & 31;
        float4 v = x4[(size_t)(row0 + r) * (Fdim / 4) + fq];
        xT[4 * fq + 0][r] = v.x;
        xT[4 * fq + 1][r] = v.y;
        xT[4 * fq + 2][r] = v.z;
        xT[4 * fq + 3][r] = v.w;
        float s = v.x * v.x + v.y * v.y + v.z * v.z + v.w * v.w;
#pragma unroll
        for (int sft = 1; sft < 32; sft <<= 1) s += __shfl_xor(s, sft, 64);
        if (fq == 0) xn_s[r] = s;
    }

    // ---- c staging: reg-prefetch double buffer (R4 schedule, unchanged)
    const int f4 = tid & 7;
    const int hh = tid >> 3;

    float4 pre[8];
    float cn_part[8];
#pragma unroll
    for (int p = 0; p < 8; ++p) cn_part[p] = 0.0f;

#pragma unroll
    for (int p = 0; p < 8; ++p)
        pre[p] = c4[(size_t)(hh + 64 * p) * (Fdim / 4) + f4];
#pragma unroll
    for (int p = 0; p < 8; ++p) {
        float4 v = pre[p];
        int h = hh + 64 * p;
        cT[4 * f4 + 0][h] = v.x;
        cT[4 * f4 + 1][h] = v.y;
        cT[4 * f4 + 2][h] = v.z;
        cT[4 * f4 + 3][h] = v.w;
        cn_part[p] += v.x * v.x + v.y * v.y + v.z * v.z + v.w * v.w;
    }
    __syncthreads();

    float acc[8][2];
#pragma unroll
    for (int r = 0; r < 8; ++r) { acc[r][0] = 0.0f; acc[r][1] = 0.0f; }

    for (int k = 0; k < NCH; ++k) {
        if (k + 1 < NCH) {
#pragma unroll
            for (int p = 0; p < 8; ++p)
                pre[p] = c4[(size_t)(hh + 64 * p) * (Fdim / 4) + (k + 1) * (KC / 4) + f4];
        }

        // ---- compute: wave handles f-half fh of chunk k, all 8 rows, 2 h/lane
#pragma unroll
        for (int f16 = 0; f16 < KC / 2; ++f16) {
            const int fl = fh * (KC / 2) + f16;          // chunk-local f
            const float* xrow = &xT[k * KC + fl][0];
            float4 xa = *reinterpret_cast<const float4*>(xrow);      // rows 0..3
            float4 xb = *reinterpret_cast<const float4*>(xrow + 4);  // rows 4..7
            float2 cv = *reinterpret_cast<const float2*>(&cT[fl][wh * 128 + 2 * lane]);
            acc[0][0] = fmaf(xa.x, cv.x, acc[0][0]);
            acc[0][1] = fmaf(xa.x, cv.y, acc[0][1]);
            acc[1][0] = fmaf(xa.y, cv.x, acc[1][0]);
            acc[1][1] = fmaf(xa.y, cv.y, acc[1][1]);
            acc[2][0] = fmaf(xa.z, cv.x, acc[2][0]);
            acc[2][1] = fmaf(xa.z, cv.y, acc[2][1]);
            acc[3][0] = fmaf(xa.w, cv.x, acc[3][0]);
            acc[3][1] = fmaf(xa.w, cv.y, acc[3][1]);
            acc[4][0] = fmaf(xb.x, cv.x, acc[4][0]);
            acc[4][1] = fmaf(xb.x, cv.y, acc[4][1]);
            acc[5][0] = fmaf(xb.y, cv.x, acc[5][0]);
            acc[5][1] = fmaf(xb.y, cv.y, acc[5][1]);
            acc[6][0] = fmaf(xb.z, cv.x, acc[6][0]);
            acc[6][1] = fmaf(xb.z, cv.y, acc[6][1]);
            acc[7][0] = fmaf(xb.w, cv.x, acc[7][0]);
            acc[7][1] = fmaf(xb.w, cv.y, acc[7][1]);
        }

        if (k + 1 < NCH) {
            __syncthreads();
#pragma unroll
            for (int p = 0; p < 8; ++p) {
                float4 v = pre[p];
                int h = hh + 64 * p;
                cT[4 * f4 + 0][h] = v.x;
                cT[4 * f4 + 1][h] = v.y;
                cT[4 * f4 + 2][h] = v.z;
                cT[4 * f4 + 3][h] = v.w;
                cn_part[p] += v.x * v.x + v.y * v.y + v.z * v.z + v.w * v.w;
            }
            __syncthreads();
        }
    }

    // ---- W into registers (as R8)
    float2 W2[Odim][4];
#pragma unroll
    for (int o = 0; o < Odim; ++o)
#pragma unroll
        for (int kk = 0; kk < 4; ++kk)
            W2[o][kk] = *reinterpret_cast<const float2*>(
                &W[o * Hdim + 2 * lane + 128 * kk]);

    // ---- f-half merge, part 1: fh=1 waves publish partial dots
    if (fh == 1) {
#pragma unroll
        for (int r = 0; r < 8; ++r) {
            float2 m; m.x = acc[r][0]; m.y = acc[r][1];
            *reinterpret_cast<float2*>(&rbf_s[r][wh * 128 + 2 * lane]) = m;
        }
    }

    // ---- publish center norms (unchanged)
#pragma unroll
    for (int p = 0; p < 8; ++p) {
        float s = cn_part[p];
        s += __shfl_xor(s, 1, 64);
        s += __shfl_xor(s, 2, 64);
        s += __shfl_xor(s, 4, 64);
        cn_part[p] = s;
    }
    if (f4 == 0) {
#pragma unroll
        for (int p = 0; p < 8; ++p) cn_s[hh + 64 * p] = cn_part[p];
    }
    __syncthreads();

    // ---- merge part 2 + rbf = exp(dist*scale): fh=0 waves only
    const float sg    = sigmap[0];
    const float scale = -1.0f / (2.0f * sg * sg);
    if (fh == 0) {
        float2 cn = *reinterpret_cast<const float2*>(&cn_s[wh * 128 + 2 * lane]);
#pragma unroll
        for (int r = 0; r < 8; ++r) {
            float2 m = *reinterpret_cast<const float2*>(&rbf_s[r][wh * 128 + 2 * lane]);
            float xn = xn_s[r];
            float d0 = xn + cn.x - 2.0f * (acc[r][0] + m.x);
            float d1 = xn + cn.y - 2.0f * (acc[r][1] + m.y);
            float2 rv;
            rv.x = __expf(d0 * scale);
            rv.y = __expf(d1 * scale);
            *reinterpret_cast<float2*>(&rbf_s[r][wh * 128 + 2 * lane]) = rv;
        }
    }
    __syncthreads();

    // ---- epilogue (R8): wave = row; W from regs; 3-step butterfly + 80-thread finish
    {
        const int row = wave;
        float po[Odim];
#pragma unroll
        for (int o = 0; o < Odim; ++o) po[o] = 0.0f;

#pragma unroll
        for (int kk = 0; kk < 4; ++kk) {
            float2 rv = *reinterpret_cast<const float2*>(
                &rbf_s[row][2 * lane + 128 * kk]);
#pragma unroll
            for (int o = 0; o < Odim; ++o) {
                po[o] = fmaf(rv.x, W2[o][kk].x, po[o]);
                po[o] = fmaf(rv.y, W2[o][kk].y, po[o]);
            }
        }
#pragma unroll
        for (int s = 1; s < 8; s <<= 1) {
#pragma unroll
            for (int o = 0; o < Odim; ++o)
                po[o] += __shfl_xor(po[o], s, 64);
        }
        if ((lane & 7) == 0) {
#pragma unroll
            for (int o = 0; o < Odim; ++o)
                po_s[row][lane >> 3][o] = po[o];
        }
    }
    __syncthreads();

    if (tid < BM * Odim) {
        int w = tid / Odim;
        int o = tid - w * Odim;
        float v = bias[o];
#pragma unroll
        for (int g = 0; g < 8; ++g) v += po_s[w][g][o];
        out[(size_t)(row0 + w) * Odim + o] = v;
    }
}

extern "C" void kernel_launch(void* const* d_in, const int* in_sizes, int n_in,
                              void* d_out, int out_size, void* d_ws, size_t ws_size,
                              hipStream_t stream) {
    const float* x  = (const float*)d_in[0];
    const float* c  = (const float*)d_in[1];
    const float* sg = (const float*)d_in[2];
    const float* W  = (const float*)d_in[3];
    const float* b  = (const float*)d_in[4];
    float* out      = (float*)d_out;

    const int B = in_sizes[0] / Fdim;   // 2048

    rbf_all<<<B / BM, 512, 0, stream>>>(x, c, sg, W, b, out);
}